// Round 7
// baseline (3261.153 us; speedup 1.0000x reference)
//
#include <hip/hip_runtime.h>
#include <cstdint>

typedef _Float16 half_t;
typedef _Float16 half2_t __attribute__((ext_vector_type(2)));
typedef _Float16 h8_t __attribute__((ext_vector_type(8)));
typedef float f4_t __attribute__((ext_vector_type(4)));
typedef unsigned int uint32;
typedef uint32 uv16 __attribute__((ext_vector_type(16)));

static constexpr int B_ = 64, T_ = 1024;

#define DEV __device__ __forceinline__

DEV float fdot2f(half2_t a, half2_t b, float c) {
#if __has_builtin(__builtin_amdgcn_fdot2)
  return __builtin_amdgcn_fdot2(a, b, c, false);
#else
  return fmaf((float)a.x, (float)b.x, fmaf((float)a.y, (float)b.y, c));
#endif
}

DEV float fast_rcp(float x) { return __builtin_amdgcn_rcpf(x); }
DEV float sigmf(float x) { return fast_rcp(1.f + __expf(-x)); }
DEV float tanhf_(float x) { return 1.f - 2.f * fast_rcp(1.f + __expf(2.f * x)); }
DEV uint32 pack2(float a, float b) {
  half2_t h; h.x = (half_t)a; h.y = (half_t)b;
  return __builtin_bit_cast(uint32, h);
}
DEV half2_t bch2(uint32 u) { return __builtin_bit_cast(half2_t, u); }

DEV void gload_lds16(const void* g, void* l) {
  __builtin_amdgcn_global_load_lds(
      (const __attribute__((address_space(1))) uint32*)g,
      (__attribute__((address_space(3))) uint32*)l, 16, 0, 0);
}

// select element j (compile-time) from the (va,vb) 32-dword pair
#define WSEL(va, vb, j) bch2(((j) < 16) ? (va)[(j) & 15] : (vb)[((j) - 16) & 15])

// ---------------- weight packing (f32 -> packed f16) ----------------
__global__ __launch_bounds__(256) void pack_w(
    const float* __restrict__ w_ih_f, const float* __restrict__ w_ih_b,
    const float* __restrict__ mu_w, const float* __restrict__ lv_w,
    const float* __restrict__ sw_w1,
    const float* __restrict__ w_hh_f, const float* __restrict__ w_hh_b,
    const float* __restrict__ b_ih_f, const float* __restrict__ b_ih_b,
    const float* __restrict__ b_hh_f, const float* __restrict__ b_hh_b,
    const float* __restrict__ mu_b, const float* __restrict__ lv_b,
    const float* __restrict__ sw_b1,
    uint32* __restrict__ wihf, uint32* __restrict__ wihb,
    uint32* __restrict__ wchf, uint32* __restrict__ wchb, uint32* __restrict__ wce2,
    uint32* __restrict__ whh, uint32* __restrict__ w1z,
    float* __restrict__ biasc, float* __restrict__ biasf, float* __restrict__ biasb) {
  int id = blockIdx.x * 256 + threadIdx.x;
  if (id < 98304) { wihf[id] = pack2(w_ih_f[2*id], w_ih_f[2*id+1]); return; }
  id -= 98304;
  if (id < 98304) { wihb[id] = pack2(w_ih_b[2*id], w_ih_b[2*id+1]); return; }
  id -= 98304;
  if (id < 32768) {  // wchf (256x256): h_f columns of [mu_w|lv_w|w1_h]
    int n = id >> 7, c0 = (id & 127) * 2;
    const float* p = (n < 64)  ? mu_w + n * 512 + c0
                   : (n < 128) ? lv_w + (n - 64) * 512 + c0
                               : sw_w1 + (n - 128) * 832 + 256 + c0;
    wchf[id] = pack2(p[0], p[1]); return;
  }
  id -= 32768;
  if (id < 32768) {  // wchb (256x256): h_b columns
    int n = id >> 7, c0 = (id & 127) * 2;
    const float* p = (n < 64)  ? mu_w + n * 512 + 256 + c0
                   : (n < 128) ? lv_w + (n - 64) * 512 + 256 + c0
                               : sw_w1 + (n - 128) * 832 + 512 + c0;
    wchb[id] = pack2(p[0], p[1]); return;
  }
  id -= 32768;
  if (id < 16384) {  // wce2 (128x256): w1_e rows only
    int n = id >> 7, c0 = (id & 127) * 2;
    wce2[id] = pack2(sw_w1[n * 832 + c0], sw_w1[n * 832 + c0 + 1]); return;
  }
  id -= 16384;
  if (id < 196608) {  // whh2: [d][192][512] per-thread layout
    int dd = id / 98304, q = id % 98304;
    int j = q >> 9, t2 = q & 511;
    int rr = t2 >> 2, pp = t2 & 3;
    int gi = j >> 5, ck = j & 31;
    int g = gi >> 1, i = gi & 1;
    int row = 256 * g + 2 * rr + i;
    int k0 = pp * 64 + 2 * ck;
    const float* w = dd ? w_hh_b : w_hh_f;
    whh[id] = pack2(w[row * 256 + k0], w[row * 256 + k0 + 1]);
    return;
  }
  id -= 196608;
  if (id < 4096) {  // w1z2: [64][64] thread-k layout, rows (k, k+64)
    int j = id >> 6, kk = id & 63;
    int row = (j < 32) ? kk : kk + 64;
    int jj = j & 31;
    w1z[id] = pack2(sw_w1[row * 832 + 768 + 2 * jj], sw_w1[row * 832 + 768 + 2 * jj + 1]);
    return;
  }
  id -= 4096;
  if (id < 256) {
    biasc[id] = (id < 64) ? mu_b[id] : (id < 128) ? lv_b[id - 64] : sw_b1[id - 128];
    return;
  }
  id -= 256;
  if (id < 768) { biasf[id] = b_ih_f[id] + (id < 512 ? b_hh_f[id] : 0.f); return; }
  id -= 768;
  if (id < 768) { biasb[id] = b_ih_b[id] + (id < 512 ? b_hh_b[id] : 0.f); return; }
}

// ---------------- GEMM: C(MxN) = A(MxK) * B(N,K)^T [+bias] [+=C] ----------------
template <int AF32, int ACC>
__global__ __launch_bounds__(256) void gemm_t(
    const void* __restrict__ Ap, int lda,
    const half_t* __restrict__ Bw,  // (N,K) f16 row-major
    const float* __restrict__ bias,
    half_t* __restrict__ C, int ldc, int K) {
  __shared__ __align__(16) half_t smem[16384];
  half_t* As = smem;         // [128][64]
  half_t* Bs = smem + 8192;  // [128][64]
  const int tid = threadIdx.x;
  const int lane = tid & 63, w = tid >> 6;
  const int n0 = blockIdx.x * 128, m0 = blockIdx.y * 128;
  const int r8 = lane >> 3, c8 = lane & 7;
  f4_t acc[4][4];
  f4_t zero = {0.f, 0.f, 0.f, 0.f};
#pragma unroll
  for (int i = 0; i < 4; ++i)
#pragma unroll
    for (int j = 0; j < 4; ++j) acc[i][j] = zero;
  const int wm = (w >> 1) * 64, wn = (w & 1) * 64;
  for (int ks = 0; ks < K; ks += 64) {
    if constexpr (AF32) {
      const float* Af = (const float*)Ap;
#pragma unroll
      for (int it = 0; it < 4; ++it) {
        int c = it * 256 + tid;
        int row = c >> 3, coff = (c & 7) * 8;
        const float* ap = Af + (size_t)(m0 + row) * lda + ks + coff;
        float4 v0 = *(const float4*)ap;
        float4 v1 = *(const float4*)(ap + 4);
        uint4 u;
        u.x = pack2(v0.x, v0.y); u.y = pack2(v0.z, v0.w);
        u.z = pack2(v1.x, v1.y); u.w = pack2(v1.z, v1.w);
        *(uint4*)&As[(size_t)c * 8] = u;
      }
    } else {
      const half_t* Af = (const half_t*)Ap;
#pragma unroll
      for (int c = 0; c < 4; ++c) {
        int row = w * 32 + c * 8 + r8;
        gload_lds16(Af + (size_t)(m0 + row) * lda + ks + c8 * 8, As + (w * 4 + c) * 512);
      }
    }
#pragma unroll
    for (int c = 0; c < 4; ++c) {
      int row = w * 32 + c * 8 + r8;
      gload_lds16(Bw + (size_t)(n0 + row) * K + ks + c8 * 8, Bs + (w * 4 + c) * 512);
    }
    __syncthreads();
#pragma unroll
    for (int kk = 0; kk < 2; ++kk) {
      h8_t af[4], bf[4];
      const int ko = kk * 32 + (lane >> 4) * 8;
#pragma unroll
      for (int i = 0; i < 4; ++i) af[i] = *(const h8_t*)&As[(wm + i * 16 + (lane & 15)) * 64 + ko];
#pragma unroll
      for (int j = 0; j < 4; ++j) bf[j] = *(const h8_t*)&Bs[(wn + j * 16 + (lane & 15)) * 64 + ko];
#pragma unroll
      for (int i = 0; i < 4; ++i)
#pragma unroll
        for (int j = 0; j < 4; ++j)
          acc[i][j] = __builtin_amdgcn_mfma_f32_16x16x32_f16(af[i], bf[j], acc[i][j], 0, 0, 0);
    }
    __syncthreads();
  }
  const int cl4 = lane & 15, rl4 = lane >> 4;
#pragma unroll
  for (int j = 0; j < 4; ++j) {
    float bj = bias ? bias[n0 + wn + j * 16 + cl4] : 0.f;
#pragma unroll
    for (int i = 0; i < 4; ++i)
#pragma unroll
      for (int q = 0; q < 4; ++q) {
        int rl = wm + i * 16 + rl4 * 4 + q;
        int cc = wn + j * 16 + cl4;
        smem[rl * 128 + cc] = (half_t)(acc[i][j][q] + bj);
      }
  }
  __syncthreads();
#pragma unroll
  for (int it = 0; it < 8; ++it) {
    int idx = it * 256 + tid;
    int row = idx >> 4, colc = idx & 15;
    uint4 v = *(const uint4*)&smem[row * 128 + colc * 8];
    half_t* cp = C + (size_t)(m0 + row) * ldc + n0 + colc * 8;
    if constexpr (ACC) {
      uint4 o = *(const uint4*)cp;
      h8_t vv = __builtin_bit_cast(h8_t, v) + __builtin_bit_cast(h8_t, o);
      v = __builtin_bit_cast(uint4, vv);
    }
    *(uint4*)cp = v;
  }
}

// ======== AGPR weight residency machinery ========
// X-macro over 0..191
#define W_ALL(X) \
  X(0) X(1) X(2) X(3) X(4) X(5) X(6) X(7) X(8) X(9) X(10) X(11) X(12) X(13) X(14) X(15) \
  X(16) X(17) X(18) X(19) X(20) X(21) X(22) X(23) X(24) X(25) X(26) X(27) X(28) X(29) X(30) X(31) \
  X(32) X(33) X(34) X(35) X(36) X(37) X(38) X(39) X(40) X(41) X(42) X(43) X(44) X(45) X(46) X(47) \
  X(48) X(49) X(50) X(51) X(52) X(53) X(54) X(55) X(56) X(57) X(58) X(59) X(60) X(61) X(62) X(63) \
  X(64) X(65) X(66) X(67) X(68) X(69) X(70) X(71) X(72) X(73) X(74) X(75) X(76) X(77) X(78) X(79) \
  X(80) X(81) X(82) X(83) X(84) X(85) X(86) X(87) X(88) X(89) X(90) X(91) X(92) X(93) X(94) X(95) \
  X(96) X(97) X(98) X(99) X(100) X(101) X(102) X(103) X(104) X(105) X(106) X(107) X(108) X(109) X(110) X(111) \
  X(112) X(113) X(114) X(115) X(116) X(117) X(118) X(119) X(120) X(121) X(122) X(123) X(124) X(125) X(126) X(127) \
  X(128) X(129) X(130) X(131) X(132) X(133) X(134) X(135) X(136) X(137) X(138) X(139) X(140) X(141) X(142) X(143) \
  X(144) X(145) X(146) X(147) X(148) X(149) X(150) X(151) X(152) X(153) X(154) X(155) X(156) X(157) X(158) X(159) \
  X(160) X(161) X(162) X(163) X(164) X(165) X(166) X(167) X(168) X(169) X(170) X(171) X(172) X(173) X(174) X(175) \
  X(176) X(177) X(178) X(179) X(180) X(181) X(182) X(183) X(184) X(185) X(186) X(187) X(188) X(189) X(190) X(191)

#define WDECL(n) uint32 wa##n;
#define WLOAD(n) asm volatile("v_accvgpr_write_b32 %0, %1" : "=a"(wa##n) : "v"(wp[(n) * 512]));
// read AGPR -> VGPR temp -> dot2 accumulate
#define DOT(W, hh, acc)                                                  \
  do {                                                                   \
    uint32 _t;                                                           \
    asm volatile("v_accvgpr_read_b32 %0, %1" : "=v"(_t) : "a"(W));       \
    acc = fdot2f(bch2(_t), (hh), (acc));                                 \
  } while (0)
// six gates for one (j) column: j, j+32, j+64, j+96, j+128, j+160
#define SIX(j0, j1, j2, j3, j4, j5, hh)  \
  DOT(wa##j0, hh, a00); DOT(wa##j1, hh, a10); DOT(wa##j2, hh, a01); \
  DOT(wa##j3, hh, a11); DOT(wa##j4, hh, a02); DOT(wa##j5, hh, a12);

// ---------------- GRU recurrence: weights resident in AGPRs ----------------
// 128 WGs = (b, dir); 512 threads = 128 r-groups (2 hidden units) x 4 K-slices.
__global__ __attribute__((amdgpu_flat_work_group_size(512, 512)))
__attribute__((amdgpu_waves_per_eu(1, 2))) void gru_rec(
    uint32* __restrict__ xp,          // [2][B][T][384] dwords (f16 pairs)
    const uint32* __restrict__ whh2,  // [2][192][512]
    const float* __restrict__ bhh_f, const float* __restrict__ bhh_b) {
  const int wg = blockIdx.x;
  const int d = wg >> 6, b = wg & 63;
  const int tid = threadIdx.x;
  const int r = tid >> 2, p = tid & 3;
  __shared__ uint32 hb[2][144];  // 4 slices x (32 data + 4 pad) dwords
  if (tid < 144) { hb[0][tid] = 0; hb[1][tid] = 0; }
  W_ALL(WDECL)
  {
    const uint32* wp = whh2 + (size_t)d * 98304 + tid;
    W_ALL(WLOAD)
  }
  const float* bhh = d ? bhh_b : bhh_f;
  const float bhn0 = bhh[512 + 2 * r], bhn1 = bhh[512 + 2 * r + 1];
  uint32* xpu = xp + ((size_t)d * B_ + b) * T_ * 384;
  float h0 = 0.f, h1 = 0.f;
  const int dt = d ? -1 : 1;
  int t = d ? (T_ - 1) : 0;
  uint32 xr_n = 0, xz_n = 0, xn_n = 0;
  if (p == 0) {
    const uint32* rowp = xpu + (size_t)t * 384;
    xr_n = rowp[r]; xz_n = rowp[128 + r]; xn_n = rowp[256 + r];
  }
  const int rdbase = p * 36;
  const int wslice = (r >> 5) * 36 + (r & 31);
  __syncthreads();
  for (int step = 0; step < T_; ++step) {
    const int cur = step & 1;
    const uint32 xr = xr_n, xz = xz_n, xn = xn_n;
    const int tn = (step < T_ - 1) ? (t + dt) : t;
    if (p == 0) {
      const uint32* rowp = xpu + (size_t)tn * 384;
      xr_n = rowp[r]; xz_n = rowp[128 + r]; xn_n = rowp[256 + r];
    }
    float a00 = 0, a10 = 0, a01 = 0, a11 = 0, a02 = 0, a12 = 0;
    const uint32* hc = &hb[cur][rdbase];
    {  // c = 0 : j = 0..7
      uint4 u0 = *(const uint4*)(hc + 0);
      uint4 u1 = *(const uint4*)(hc + 4);
      half2_t g0 = bch2(u0.x), g1 = bch2(u0.y), g2 = bch2(u0.z), g3 = bch2(u0.w);
      half2_t g4 = bch2(u1.x), g5 = bch2(u1.y), g6 = bch2(u1.z), g7 = bch2(u1.w);
      SIX(0, 32, 64, 96, 128, 160, g0)
      SIX(1, 33, 65, 97, 129, 161, g1)
      SIX(2, 34, 66, 98, 130, 162, g2)
      SIX(3, 35, 67, 99, 131, 163, g3)
      SIX(4, 36, 68, 100, 132, 164, g4)
      SIX(5, 37, 69, 101, 133, 165, g5)
      SIX(6, 38, 70, 102, 134, 166, g6)
      SIX(7, 39, 71, 103, 135, 167, g7)
    }
    {  // c = 1 : j = 8..15
      uint4 u0 = *(const uint4*)(hc + 8);
      uint4 u1 = *(const uint4*)(hc + 12);
      half2_t g0 = bch2(u0.x), g1 = bch2(u0.y), g2 = bch2(u0.z), g3 = bch2(u0.w);
      half2_t g4 = bch2(u1.x), g5 = bch2(u1.y), g6 = bch2(u1.z), g7 = bch2(u1.w);
      SIX(8, 40, 72, 104, 136, 168, g0)
      SIX(9, 41, 73, 105, 137, 169, g1)
      SIX(10, 42, 74, 106, 138, 170, g2)
      SIX(11, 43, 75, 107, 139, 171, g3)
      SIX(12, 44, 76, 108, 140, 172, g4)
      SIX(13, 45, 77, 109, 141, 173, g5)
      SIX(14, 46, 78, 110, 142, 174, g6)
      SIX(15, 47, 79, 111, 143, 175, g7)
    }
    {  // c = 2 : j = 16..23
      uint4 u0 = *(const uint4*)(hc + 16);
      uint4 u1 = *(const uint4*)(hc + 20);
      half2_t g0 = bch2(u0.x), g1 = bch2(u0.y), g2 = bch2(u0.z), g3 = bch2(u0.w);
      half2_t g4 = bch2(u1.x), g5 = bch2(u1.y), g6 = bch2(u1.z), g7 = bch2(u1.w);
      SIX(16, 48, 80, 112, 144, 176, g0)
      SIX(17, 49, 81, 113, 145, 177, g1)
      SIX(18, 50, 82, 114, 146, 178, g2)
      SIX(19, 51, 83, 115, 147, 179, g3)
      SIX(20, 52, 84, 116, 148, 180, g4)
      SIX(21, 53, 85, 117, 149, 181, g5)
      SIX(22, 54, 86, 118, 150, 182, g6)
      SIX(23, 55, 87, 119, 151, 183, g7)
    }
    {  // c = 3 : j = 24..31
      uint4 u0 = *(const uint4*)(hc + 24);
      uint4 u1 = *(const uint4*)(hc + 28);
      half2_t g0 = bch2(u0.x), g1 = bch2(u0.y), g2 = bch2(u0.z), g3 = bch2(u0.w);
      half2_t g4 = bch2(u1.x), g5 = bch2(u1.y), g6 = bch2(u1.z), g7 = bch2(u1.w);
      SIX(24, 56, 88, 120, 152, 184, g0)
      SIX(25, 57, 89, 121, 153, 185, g1)
      SIX(26, 58, 90, 122, 154, 186, g2)
      SIX(27, 59, 91, 123, 155, 187, g3)
      SIX(28, 60, 92, 124, 156, 188, g4)
      SIX(29, 61, 93, 125, 157, 189, g5)
      SIX(30, 62, 94, 126, 158, 190, g6)
      SIX(31, 63, 95, 127, 159, 191, g7)
    }
    a00 += __shfl_xor(a00, 1); a00 += __shfl_xor(a00, 2);
    a10 += __shfl_xor(a10, 1); a10 += __shfl_xor(a10, 2);
    a01 += __shfl_xor(a01, 1); a01 += __shfl_xor(a01, 2);
    a11 += __shfl_xor(a11, 1); a11 += __shfl_xor(a11, 2);
    a02 += __shfl_xor(a02, 1); a02 += __shfl_xor(a02, 2);
    a12 += __shfl_xor(a12, 1); a12 += __shfl_xor(a12, 2);
    if (p == 0) {
      half2_t xrv = bch2(xr), xzv = bch2(xz), xnv = bch2(xn);
      float r0 = sigmf((float)xrv.x + a00);
      float z0 = sigmf((float)xzv.x + a01);
      float n0 = tanhf_((float)xnv.x + r0 * (a02 + bhn0));
      h0 = (1.f - z0) * n0 + z0 * h0;
      float r1 = sigmf((float)xrv.y + a10);
      float z1 = sigmf((float)xzv.y + a11);
      float n1 = tanhf_((float)xnv.y + r1 * (a12 + bhn1));
      h1 = (1.f - z1) * n1 + z1 * h1;
      uint32 ph = pack2(h0, h1);
      hb[cur ^ 1][wslice] = ph;
      xpu[(size_t)t * 384 + r] = ph;  // in-place h store (xr slot dead)
    }
    __syncthreads();
    t = tn;
  }
}

// ---------------- z_tilde + KL partials ----------------
__global__ __launch_bounds__(256) void zkl(const half_t* __restrict__ hp,  // stride 768
                                           const float* __restrict__ eps,
                                           float* __restrict__ ztil,
                                           float* __restrict__ klp) {
  const int blk = blockIdx.x, tid = threadIdx.x;
  const size_t bt = (size_t)blk * 4 + (tid >> 6);
  const int j = tid & 63;
  float mu = (float)hp[bt * 768 + j];
  float lv = (float)hp[bt * 768 + 64 + j];
  float ev = eps[bt * 64 + j];
  ztil[bt * 64 + j] = mu + __expf(0.5f * lv) * ev;
  float term = 1.f + lv - mu * mu - __expf(lv);
#pragma unroll
  for (int s = 1; s < 64; s <<= 1) term += __shfl_xor(term, s);
  __shared__ float red[4];
  if ((tid & 63) == 0) red[tid >> 6] = term;
  __syncthreads();
  if (tid == 0) klp[blk] = red[0] + red[1] + red[2] + red[3];
}

__global__ __launch_bounds__(256) void klred(const float* __restrict__ klp,
                                             float* __restrict__ out) {
  const int tid = threadIdx.x;
  float s = 0.f;
  for (int i = tid; i < 16384; i += 256) s += klp[i];
#pragma unroll
  for (int st = 1; st < 64; st <<= 1) s += __shfl_xor(s, st);
  __shared__ float red[4];
  if ((tid & 63) == 0) red[tid >> 6] = s;
  __syncthreads();
  if (tid == 0) out[0] = (red[0] + red[1] + red[2] + red[3]) * (-0.5f / 65536.f);
}

// ---------------- sequential z-scan: ONE wave per batch element ----------------
__global__ __launch_bounds__(64, 4) void z_scan(
    const half_t* __restrict__ hp,  // pre at col offset 128, stride 768
    const float* __restrict__ zt_arr,
    const uint32* __restrict__ w1z,  // [64][64] thread-k layout
    const float* __restrict__ sw_w2, const float* __restrict__ sw_b2,
    float* __restrict__ z_out, float* __restrict__ beta_out) {
  const int b = blockIdx.x;
  const int k = threadIdx.x;  // 0..63; owns hid rows k and k+64
  uv16 z0a, z0b, z1a, z1b;    // 64 weights in named vectors
  {
#define LDZ(vec, base)                                    \
  _Pragma("unroll") for (int e = 0; e < 16; ++e) vec[e] = \
      w1z[((base) + e) * 64 + k];
    LDZ(z0a, 0); LDZ(z0b, 16); LDZ(z1a, 32); LDZ(z1b, 48);
#undef LDZ
  }
  const float w2k0 = sw_w2[k], w2k1 = sw_w2[k + 64], b2 = sw_b2[0];
  __shared__ uint32 zbuf[2][32];
  if (k < 32) { zbuf[0][k] = 0; zbuf[1][k] = 0; }
  __syncthreads();
  float zf = 0.f;
  const size_t bt0 = (size_t)b * T_;
  float pre0n = (float)hp[bt0 * 768 + 128 + k];
  float pre1n = (float)hp[bt0 * 768 + 192 + k];
  float ztn = zt_arr[bt0 * 64 + k];
  for (int t = 0; t < T_; ++t) {
    const int cur = t & 1;
    const float pre0 = pre0n, pre1 = pre1n, zt = ztn;
    const int tn = (t < T_ - 1) ? t + 1 : t;
    pre0n = (float)hp[(bt0 + tn) * 768 + 128 + k];
    pre1n = (float)hp[(bt0 + tn) * 768 + 192 + k];
    ztn = zt_arr[(bt0 + tn) * 64 + k];
    float a0 = 0, a1 = 0, a2 = 0, a3 = 0;
#pragma unroll
    for (int q = 0; q < 8; ++q) {
      uint4 u = *(const uint4*)&zbuf[cur][q * 4];
      const int m = q * 4;
      a0 = fdot2f(WSEL(z0a, z0b, m),     bch2(u.x), a0);
      a1 = fdot2f(WSEL(z0a, z0b, m + 1), bch2(u.y), a1);
      a0 = fdot2f(WSEL(z0a, z0b, m + 2), bch2(u.z), a0);
      a1 = fdot2f(WSEL(z0a, z0b, m + 3), bch2(u.w), a1);
      a2 = fdot2f(WSEL(z1a, z1b, m),     bch2(u.x), a2);
      a3 = fdot2f(WSEL(z1a, z1b, m + 1), bch2(u.y), a3);
      a2 = fdot2f(WSEL(z1a, z1b, m + 2), bch2(u.z), a2);
      a3 = fdot2f(WSEL(z1a, z1b, m + 3), bch2(u.w), a3);
    }
    float hid0 = fmaxf(pre0 + a0 + a1, 0.f);
    float hid1 = fmaxf(pre1 + a2 + a3, 0.f);
    float v = fmaf(hid0, w2k0, hid1 * w2k1);
#pragma unroll
    for (int s = 1; s < 64; s <<= 1) v += __shfl_xor(v, s);
    const float beta = sigmf(v + b2);
    zf = beta * zt + (1.f - beta) * zf;
    z_out[(bt0 + t) * 64 + k] = zf;
    if (k == 0) beta_out[bt0 + t] = beta;
    float zo = __shfl_xor(zf, 1);
    if ((k & 1) == 0) zbuf[cur ^ 1][k >> 1] = pack2(zf, zo);
    asm volatile("s_waitcnt lgkmcnt(0)" ::: "memory");  // single-wave LDS ordering
  }
}

extern "C" void kernel_launch(void* const* d_in, const int* in_sizes, int n_in,
                              void* d_out, int out_size, void* d_ws, size_t ws_size,
                              hipStream_t stream) {
  (void)in_sizes; (void)n_in; (void)out_size;
  const float* e_seq  = (const float*)d_in[0];
  const float* eps    = (const float*)d_in[1];
  const float* w_ih_f = (const float*)d_in[2];
  const float* w_hh_f = (const float*)d_in[3];
  const float* b_ih_f = (const float*)d_in[4];
  const float* b_hh_f = (const float*)d_in[5];
  const float* w_ih_b = (const float*)d_in[6];
  const float* w_hh_b = (const float*)d_in[7];
  const float* b_ih_b = (const float*)d_in[8];
  const float* b_hh_b = (const float*)d_in[9];
  const float* mu_w   = (const float*)d_in[10];
  const float* mu_b   = (const float*)d_in[11];
  const float* lv_w   = (const float*)d_in[12];
  const float* lv_b   = (const float*)d_in[13];
  const float* sw_w1  = (const float*)d_in[14];
  const float* sw_b1  = (const float*)d_in[15];
  const float* sw_w2  = (const float*)d_in[16];
  const float* sw_b2  = (const float*)d_in[17];

  // workspace: [0,100663296) xpf; [100663296,201326592) xpb; tail: packed weights
  const size_t NEED = 201326592 + 1924096;
  if (ws_size < NEED) return;
  char* ws = (char*)d_ws;
  half_t* xpf = (half_t*)ws;
  half_t* xpb = (half_t*)(ws + 100663296);
  half_t* hp  = xpf + 512;                      // heads cols [512,768), stride 768
  float*  ztil = (float*)(ws + 100663296);      // alias xpb (dead after head passes)
  float*  klp  = (float*)(ws + 100663296 + 16777216);
  char* wr = ws + 201326592;
  uint32* wihf  = (uint32*)(wr);                //  393216 B
  uint32* wihb  = (uint32*)(wr + 393216);       //  393216 B
  uint32* wchf  = (uint32*)(wr + 786432);       //  131072 B
  uint32* wchb  = (uint32*)(wr + 917504);       //  131072 B
  uint32* wce2  = (uint32*)(wr + 1048576);      //   65536 B
  uint32* whh2  = (uint32*)(wr + 1114112);      //  786432 B
  uint32* w1z2  = (uint32*)(wr + 1900544);      //   16384 B
  float*  biasc = (float*)(wr + 1916928);       //    1024 B
  float*  biasf = (float*)(wr + 1917952);       //    3072 B
  float*  biasb = (float*)(wr + 1921024);       //    3072 B

  pack_w<<<1879, 256, 0, stream>>>(w_ih_f, w_ih_b, mu_w, lv_w, sw_w1, w_hh_f, w_hh_b,
                                   b_ih_f, b_ih_b, b_hh_f, b_hh_b, mu_b, lv_b, sw_b1,
                                   wihf, wihb, wchf, wchb, wce2, whh2, w1z2,
                                   biasc, biasf, biasb);
  gemm_t<1, 0><<<dim3(6, 512), 256, 0, stream>>>(e_seq, 256, (const half_t*)wihf, biasf, xpf, 768, 256);
  gemm_t<1, 0><<<dim3(6, 512), 256, 0, stream>>>(e_seq, 256, (const half_t*)wihb, biasb, xpb, 768, 256);
  gru_rec<<<128, 512, 0, stream>>>((uint32*)ws, whh2, b_hh_f, b_hh_b);
  gemm_t<0, 0><<<dim3(2, 512), 256, 0, stream>>>(xpf, 768, (const half_t*)wchf, biasc, hp, 768, 256);
  gemm_t<0, 1><<<dim3(2, 512), 256, 0, stream>>>(xpb, 768, (const half_t*)wchb, nullptr, hp, 768, 256);
  gemm_t<1, 1><<<dim3(1, 512), 256, 0, stream>>>(e_seq, 256, (const half_t*)wce2, nullptr, hp + 128, 768, 256);
  zkl<<<16384, 256, 0, stream>>>(hp, eps, ztil, klp);
  klred<<<1, 256, 0, stream>>>(klp, (float*)d_out + 4194304);
  z_scan<<<64, 64, 0, stream>>>(hp, ztil, w1z2, sw_w2, sw_b2, (float*)d_out, (float*)d_out + 4194305);
}

// Round 9
// 2716.658 us; speedup vs baseline: 1.2004x; 1.2004x over previous
//
#include <hip/hip_runtime.h>
#include <cstdint>

typedef _Float16 half_t;
typedef _Float16 half2_t __attribute__((ext_vector_type(2)));
typedef _Float16 h8_t __attribute__((ext_vector_type(8)));
typedef float f4_t __attribute__((ext_vector_type(4)));
typedef unsigned int uint32;
typedef uint32 uv16 __attribute__((ext_vector_type(16)));

static constexpr int B_ = 64, T_ = 1024;

#define DEV __device__ __forceinline__

DEV float fdot2f(half2_t a, half2_t b, float c) {
#if __has_builtin(__builtin_amdgcn_fdot2)
  return __builtin_amdgcn_fdot2(a, b, c, false);
#else
  return fmaf((float)a.x, (float)b.x, fmaf((float)a.y, (float)b.y, c));
#endif
}

DEV float fast_rcp(float x) { return __builtin_amdgcn_rcpf(x); }
DEV float sigmf(float x) { return fast_rcp(1.f + __expf(-x)); }
DEV float tanhf_(float x) { return 1.f - 2.f * fast_rcp(1.f + __expf(2.f * x)); }
DEV uint32 pack2(float a, float b) {
  half2_t h; h.x = (half_t)a; h.y = (half_t)b;
  return __builtin_bit_cast(uint32, h);
}
DEV half2_t bch2(uint32 u) { return __builtin_bit_cast(half2_t, u); }

DEV void gload_lds16(const void* g, void* l) {
  __builtin_amdgcn_global_load_lds(
      (const __attribute__((address_space(1))) uint32*)g,
      (__attribute__((address_space(3))) uint32*)l, 16, 0, 0);
}

// select element j (compile-time) from the (va,vb) 32-dword pair
#define WSEL(va, vb, j) bch2(((j) < 16) ? (va)[(j) & 15] : (vb)[((j) - 16) & 15])

// ---------------- weight packing (f32 -> packed f16) ----------------
__global__ __launch_bounds__(256) void pack_w(
    const float* __restrict__ w_ih_f, const float* __restrict__ w_ih_b,
    const float* __restrict__ mu_w, const float* __restrict__ lv_w,
    const float* __restrict__ sw_w1,
    const float* __restrict__ w_hh_f, const float* __restrict__ w_hh_b,
    const float* __restrict__ b_ih_f, const float* __restrict__ b_ih_b,
    const float* __restrict__ b_hh_f, const float* __restrict__ b_hh_b,
    const float* __restrict__ mu_b, const float* __restrict__ lv_b,
    const float* __restrict__ sw_b1,
    uint32* __restrict__ wihf, uint32* __restrict__ wihb,
    uint32* __restrict__ wchf, uint32* __restrict__ wchb, uint32* __restrict__ wce2,
    uint32* __restrict__ whh, uint32* __restrict__ w1z,
    float* __restrict__ biasc, float* __restrict__ biasf, float* __restrict__ biasb) {
  int id = blockIdx.x * 256 + threadIdx.x;
  if (id < 98304) { wihf[id] = pack2(w_ih_f[2*id], w_ih_f[2*id+1]); return; }
  id -= 98304;
  if (id < 98304) { wihb[id] = pack2(w_ih_b[2*id], w_ih_b[2*id+1]); return; }
  id -= 98304;
  if (id < 32768) {  // wchf (256x256): h_f columns of [mu_w|lv_w|w1_h]
    int n = id >> 7, c0 = (id & 127) * 2;
    const float* p = (n < 64)  ? mu_w + n * 512 + c0
                   : (n < 128) ? lv_w + (n - 64) * 512 + c0
                               : sw_w1 + (n - 128) * 832 + 256 + c0;
    wchf[id] = pack2(p[0], p[1]); return;
  }
  id -= 32768;
  if (id < 32768) {  // wchb (256x256): h_b columns
    int n = id >> 7, c0 = (id & 127) * 2;
    const float* p = (n < 64)  ? mu_w + n * 512 + 256 + c0
                   : (n < 128) ? lv_w + (n - 64) * 512 + 256 + c0
                               : sw_w1 + (n - 128) * 832 + 512 + c0;
    wchb[id] = pack2(p[0], p[1]); return;
  }
  id -= 32768;
  if (id < 16384) {  // wce2 (128x256): w1_e rows only
    int n = id >> 7, c0 = (id & 127) * 2;
    wce2[id] = pack2(sw_w1[n * 832 + c0], sw_w1[n * 832 + c0 + 1]); return;
  }
  id -= 16384;
  if (id < 196608) {  // whh2: [d][192][512] per-thread layout
    int dd = id / 98304, q = id % 98304;
    int j = q >> 9, t2 = q & 511;
    int rr = t2 >> 2, pp = t2 & 3;
    int gi = j >> 5, ck = j & 31;
    int g = gi >> 1, i = gi & 1;
    int row = 256 * g + 2 * rr + i;
    int k0 = pp * 64 + 2 * ck;
    const float* w = dd ? w_hh_b : w_hh_f;
    whh[id] = pack2(w[row * 256 + k0], w[row * 256 + k0 + 1]);
    return;
  }
  id -= 196608;
  if (id < 4096) {  // w1z2: [64][64] thread-k layout, rows (k, k+64)
    int j = id >> 6, kk = id & 63;
    int row = (j < 32) ? kk : kk + 64;
    int jj = j & 31;
    w1z[id] = pack2(sw_w1[row * 832 + 768 + 2 * jj], sw_w1[row * 832 + 768 + 2 * jj + 1]);
    return;
  }
  id -= 4096;
  if (id < 256) {
    biasc[id] = (id < 64) ? mu_b[id] : (id < 128) ? lv_b[id - 64] : sw_b1[id - 128];
    return;
  }
  id -= 256;
  if (id < 768) { biasf[id] = b_ih_f[id] + (id < 512 ? b_hh_f[id] : 0.f); return; }
  id -= 768;
  if (id < 768) { biasb[id] = b_ih_b[id] + (id < 512 ? b_hh_b[id] : 0.f); return; }
}

// ---------------- GEMM: C(MxN) = A(MxK) * B(N,K)^T [+bias] [+=C] ----------------
template <int AF32, int ACC>
__global__ __launch_bounds__(256) void gemm_t(
    const void* __restrict__ Ap, int lda,
    const half_t* __restrict__ Bw,  // (N,K) f16 row-major
    const float* __restrict__ bias,
    half_t* __restrict__ C, int ldc, int K) {
  __shared__ __align__(16) half_t smem[16384];
  half_t* As = smem;         // [128][64]
  half_t* Bs = smem + 8192;  // [128][64]
  const int tid = threadIdx.x;
  const int lane = tid & 63, w = tid >> 6;
  const int n0 = blockIdx.x * 128, m0 = blockIdx.y * 128;
  const int r8 = lane >> 3, c8 = lane & 7;
  f4_t acc[4][4];
  f4_t zero = {0.f, 0.f, 0.f, 0.f};
#pragma unroll
  for (int i = 0; i < 4; ++i)
#pragma unroll
    for (int j = 0; j < 4; ++j) acc[i][j] = zero;
  const int wm = (w >> 1) * 64, wn = (w & 1) * 64;
  for (int ks = 0; ks < K; ks += 64) {
    if constexpr (AF32) {
      const float* Af = (const float*)Ap;
#pragma unroll
      for (int it = 0; it < 4; ++it) {
        int c = it * 256 + tid;
        int row = c >> 3, coff = (c & 7) * 8;
        const float* ap = Af + (size_t)(m0 + row) * lda + ks + coff;
        float4 v0 = *(const float4*)ap;
        float4 v1 = *(const float4*)(ap + 4);
        uint4 u;
        u.x = pack2(v0.x, v0.y); u.y = pack2(v0.z, v0.w);
        u.z = pack2(v1.x, v1.y); u.w = pack2(v1.z, v1.w);
        *(uint4*)&As[(size_t)c * 8] = u;
      }
    } else {
      const half_t* Af = (const half_t*)Ap;
#pragma unroll
      for (int c = 0; c < 4; ++c) {
        int row = w * 32 + c * 8 + r8;
        gload_lds16(Af + (size_t)(m0 + row) * lda + ks + c8 * 8, As + (w * 4 + c) * 512);
      }
    }
#pragma unroll
    for (int c = 0; c < 4; ++c) {
      int row = w * 32 + c * 8 + r8;
      gload_lds16(Bw + (size_t)(n0 + row) * K + ks + c8 * 8, Bs + (w * 4 + c) * 512);
    }
    __syncthreads();
#pragma unroll
    for (int kk = 0; kk < 2; ++kk) {
      h8_t af[4], bf[4];
      const int ko = kk * 32 + (lane >> 4) * 8;
#pragma unroll
      for (int i = 0; i < 4; ++i) af[i] = *(const h8_t*)&As[(wm + i * 16 + (lane & 15)) * 64 + ko];
#pragma unroll
      for (int j = 0; j < 4; ++j) bf[j] = *(const h8_t*)&Bs[(wn + j * 16 + (lane & 15)) * 64 + ko];
#pragma unroll
      for (int i = 0; i < 4; ++i)
#pragma unroll
        for (int j = 0; j < 4; ++j)
          acc[i][j] = __builtin_amdgcn_mfma_f32_16x16x32_f16(af[i], bf[j], acc[i][j], 0, 0, 0);
    }
    __syncthreads();
  }
  const int cl4 = lane & 15, rl4 = lane >> 4;
#pragma unroll
  for (int j = 0; j < 4; ++j) {
    float bj = bias ? bias[n0 + wn + j * 16 + cl4] : 0.f;
#pragma unroll
    for (int i = 0; i < 4; ++i)
#pragma unroll
      for (int q = 0; q < 4; ++q) {
        int rl = wm + i * 16 + rl4 * 4 + q;
        int cc = wn + j * 16 + cl4;
        smem[rl * 128 + cc] = (half_t)(acc[i][j][q] + bj);
      }
  }
  __syncthreads();
#pragma unroll
  for (int it = 0; it < 8; ++it) {
    int idx = it * 256 + tid;
    int row = idx >> 4, colc = idx & 15;
    uint4 v = *(const uint4*)&smem[row * 128 + colc * 8];
    half_t* cp = C + (size_t)(m0 + row) * ldc + n0 + colc * 8;
    if constexpr (ACC) {
      uint4 o = *(const uint4*)cp;
      h8_t vv = __builtin_bit_cast(h8_t, v) + __builtin_bit_cast(h8_t, o);
      v = __builtin_bit_cast(uint4, vv);
    }
    *(uint4*)cp = v;
  }
}

// ======== hybrid VGPR/AGPR weight residency ========
// AGPR names for j = 64..191 (128 regs)
#define WA_ALL(X) \
  X(64) X(65) X(66) X(67) X(68) X(69) X(70) X(71) X(72) X(73) X(74) X(75) X(76) X(77) X(78) X(79) \
  X(80) X(81) X(82) X(83) X(84) X(85) X(86) X(87) X(88) X(89) X(90) X(91) X(92) X(93) X(94) X(95) \
  X(96) X(97) X(98) X(99) X(100) X(101) X(102) X(103) X(104) X(105) X(106) X(107) X(108) X(109) X(110) X(111) \
  X(112) X(113) X(114) X(115) X(116) X(117) X(118) X(119) X(120) X(121) X(122) X(123) X(124) X(125) X(126) X(127) \
  X(128) X(129) X(130) X(131) X(132) X(133) X(134) X(135) X(136) X(137) X(138) X(139) X(140) X(141) X(142) X(143) \
  X(144) X(145) X(146) X(147) X(148) X(149) X(150) X(151) X(152) X(153) X(154) X(155) X(156) X(157) X(158) X(159) \
  X(160) X(161) X(162) X(163) X(164) X(165) X(166) X(167) X(168) X(169) X(170) X(171) X(172) X(173) X(174) X(175) \
  X(176) X(177) X(178) X(179) X(180) X(181) X(182) X(183) X(184) X(185) X(186) X(187) X(188) X(189) X(190) X(191)

#define WDECL(n) uint32 wa##n;
#define WLOAD(n) asm volatile("v_accvgpr_write_b32 %0, %1" : "=a"(wa##n) : "v"(wp[(n) * 512]));
// batched volatile AGPR->VGPR read (volatile: prevents hoisting all reads out of loop)
#define ARD(T, W) asm volatile("v_accvgpr_read_b32 %0, %1" : "=v"(T) : "a"(W));
// VGPR weight select (compile-time j in 0..63 across wv0..wv3)
#define WV(j) bch2(((j) < 16) ? wv0[(j) & 15] : ((j) < 32) ? wv1[(j) & 15] \
                 : ((j) < 48) ? wv2[(j) & 15] : wv3[(j) & 15])
// one h-column: 4 AGPR reads batched, 2 VGPR dots (cover latency), 4 AGPR dots
#define COL(j, A0, A1, A2, A3, hh)          \
  {                                         \
    uint32 t0, t1, t2, t3;                  \
    ARD(t0, A0) ARD(t1, A1) ARD(t2, A2) ARD(t3, A3) \
    a00 = fdot2f(WV(j), hh, a00);           \
    a10 = fdot2f(WV((j) + 32), hh, a10);    \
    a01 = fdot2f(bch2(t0), hh, a01);        \
    a11 = fdot2f(bch2(t1), hh, a11);        \
    a02 = fdot2f(bch2(t2), hh, a02);        \
    a12 = fdot2f(bch2(t3), hh, a12);        \
  }

// ---------------- GRU recurrence: 64 weights in VGPR + 128 in AGPR ----------------
// 128 WGs = (b, dir); 512 threads = 128 r-groups (2 hidden units) x 4 K-slices.
__global__ __launch_bounds__(512) void gru_rec(
    uint32* __restrict__ xp,          // [2][B][T][384] dwords (f16 pairs)
    const uint32* __restrict__ whh2,  // [2][192][512]
    const float* __restrict__ bhh_f, const float* __restrict__ bhh_b) {
  const int wg = blockIdx.x;
  const int d = wg >> 6, b = wg & 63;
  const int tid = threadIdx.x;
  const int r = tid >> 2, p = tid & 3;
  __shared__ uint32 hb[2][144];  // 4 slices x (32 data + 4 pad) dwords
  if (tid < 144) { hb[0][tid] = 0; hb[1][tid] = 0; }
  uv16 wv0, wv1, wv2, wv3;  // weights j=0..63 (gates a00, a10)
  WA_ALL(WDECL)
  {
    const uint32* wp = whh2 + (size_t)d * 98304 + tid;
#pragma unroll
    for (int e = 0; e < 16; ++e) {
      wv0[e] = wp[(size_t)(e) * 512];
      wv1[e] = wp[(size_t)(16 + e) * 512];
      wv2[e] = wp[(size_t)(32 + e) * 512];
      wv3[e] = wp[(size_t)(48 + e) * 512];
    }
    WA_ALL(WLOAD)
  }
  const float* bhh = d ? bhh_b : bhh_f;
  const float bhn0 = bhh[512 + 2 * r], bhn1 = bhh[512 + 2 * r + 1];
  uint32* xpu = xp + ((size_t)d * B_ + b) * T_ * 384;
  float h0 = 0.f, h1 = 0.f;
  const int dt = d ? -1 : 1;
  int t = d ? (T_ - 1) : 0;
  uint32 xr_n = 0, xz_n = 0, xn_n = 0;
  if (p == 0) {
    const uint32* rowp = xpu + (size_t)t * 384;
    xr_n = rowp[r]; xz_n = rowp[128 + r]; xn_n = rowp[256 + r];
  }
  const int rdbase = p * 36;
  const int wslice = (r >> 5) * 36 + (r & 31);
  __syncthreads();
  for (int step = 0; step < T_; ++step) {
    const int cur = step & 1;
    const uint32 xr = xr_n, xz = xz_n, xn = xn_n;
    const int tn = (step < T_ - 1) ? (t + dt) : t;
    if (p == 0) {
      const uint32* rowp = xpu + (size_t)tn * 384;
      xr_n = rowp[r]; xz_n = rowp[128 + r]; xn_n = rowp[256 + r];
    }
    float a00 = 0, a10 = 0, a01 = 0, a11 = 0, a02 = 0, a12 = 0;
    const uint32* hc = &hb[cur][rdbase];
    {  // columns 0..7
      uint4 u0 = *(const uint4*)(hc + 0);
      uint4 u1 = *(const uint4*)(hc + 4);
      half2_t g0 = bch2(u0.x), g1 = bch2(u0.y), g2 = bch2(u0.z), g3 = bch2(u0.w);
      half2_t g4 = bch2(u1.x), g5 = bch2(u1.y), g6 = bch2(u1.z), g7 = bch2(u1.w);
      COL(0, wa64, wa96, wa128, wa160, g0)
      COL(1, wa65, wa97, wa129, wa161, g1)
      COL(2, wa66, wa98, wa130, wa162, g2)
      COL(3, wa67, wa99, wa131, wa163, g3)
      COL(4, wa68, wa100, wa132, wa164, g4)
      COL(5, wa69, wa101, wa133, wa165, g5)
      COL(6, wa70, wa102, wa134, wa166, g6)
      COL(7, wa71, wa103, wa135, wa167, g7)
    }
    {  // columns 8..15
      uint4 u0 = *(const uint4*)(hc + 8);
      uint4 u1 = *(const uint4*)(hc + 12);
      half2_t g0 = bch2(u0.x), g1 = bch2(u0.y), g2 = bch2(u0.z), g3 = bch2(u0.w);
      half2_t g4 = bch2(u1.x), g5 = bch2(u1.y), g6 = bch2(u1.z), g7 = bch2(u1.w);
      COL(8, wa72, wa104, wa136, wa168, g0)
      COL(9, wa73, wa105, wa137, wa169, g1)
      COL(10, wa74, wa106, wa138, wa170, g2)
      COL(11, wa75, wa107, wa139, wa171, g3)
      COL(12, wa76, wa108, wa140, wa172, g4)
      COL(13, wa77, wa109, wa141, wa173, g5)
      COL(14, wa78, wa110, wa142, wa174, g6)
      COL(15, wa79, wa111, wa143, wa175, g7)
    }
    {  // columns 16..23
      uint4 u0 = *(const uint4*)(hc + 16);
      uint4 u1 = *(const uint4*)(hc + 20);
      half2_t g0 = bch2(u0.x), g1 = bch2(u0.y), g2 = bch2(u0.z), g3 = bch2(u0.w);
      half2_t g4 = bch2(u1.x), g5 = bch2(u1.y), g6 = bch2(u1.z), g7 = bch2(u1.w);
      COL(16, wa80, wa112, wa144, wa176, g0)
      COL(17, wa81, wa113, wa145, wa177, g1)
      COL(18, wa82, wa114, wa146, wa178, g2)
      COL(19, wa83, wa115, wa147, wa179, g3)
      COL(20, wa84, wa116, wa148, wa180, g4)
      COL(21, wa85, wa117, wa149, wa181, g5)
      COL(22, wa86, wa118, wa150, wa182, g6)
      COL(23, wa87, wa119, wa151, wa183, g7)
    }
    {  // columns 24..31
      uint4 u0 = *(const uint4*)(hc + 24);
      uint4 u1 = *(const uint4*)(hc + 28);
      half2_t g0 = bch2(u0.x), g1 = bch2(u0.y), g2 = bch2(u0.z), g3 = bch2(u0.w);
      half2_t g4 = bch2(u1.x), g5 = bch2(u1.y), g6 = bch2(u1.z), g7 = bch2(u1.w);
      COL(24, wa88, wa120, wa152, wa184, g0)
      COL(25, wa89, wa121, wa153, wa185, g1)
      COL(26, wa90, wa122, wa154, wa186, g2)
      COL(27, wa91, wa123, wa155, wa187, g3)
      COL(28, wa92, wa124, wa156, wa188, g4)
      COL(29, wa93, wa125, wa157, wa189, g5)
      COL(30, wa94, wa126, wa158, wa190, g6)
      COL(31, wa95, wa127, wa159, wa191, g7)
    }
    a00 += __shfl_xor(a00, 1); a00 += __shfl_xor(a00, 2);
    a10 += __shfl_xor(a10, 1); a10 += __shfl_xor(a10, 2);
    a01 += __shfl_xor(a01, 1); a01 += __shfl_xor(a01, 2);
    a11 += __shfl_xor(a11, 1); a11 += __shfl_xor(a11, 2);
    a02 += __shfl_xor(a02, 1); a02 += __shfl_xor(a02, 2);
    a12 += __shfl_xor(a12, 1); a12 += __shfl_xor(a12, 2);
    if (p == 0) {
      half2_t xrv = bch2(xr), xzv = bch2(xz), xnv = bch2(xn);
      float r0 = sigmf((float)xrv.x + a00);
      float z0 = sigmf((float)xzv.x + a01);
      float n0 = tanhf_((float)xnv.x + r0 * (a02 + bhn0));
      h0 = (1.f - z0) * n0 + z0 * h0;
      float r1 = sigmf((float)xrv.y + a10);
      float z1 = sigmf((float)xzv.y + a11);
      float n1 = tanhf_((float)xnv.y + r1 * (a12 + bhn1));
      h1 = (1.f - z1) * n1 + z1 * h1;
      uint32 ph = pack2(h0, h1);
      hb[cur ^ 1][wslice] = ph;
      xpu[(size_t)t * 384 + r] = ph;  // in-place h store (xr slot dead)
    }
    __syncthreads();
    t = tn;
  }
}

// ---------------- z_tilde + KL partials ----------------
__global__ __launch_bounds__(256) void zkl(const half_t* __restrict__ hp,  // stride 768
                                           const float* __restrict__ eps,
                                           float* __restrict__ ztil,
                                           float* __restrict__ klp) {
  const int blk = blockIdx.x, tid = threadIdx.x;
  const size_t bt = (size_t)blk * 4 + (tid >> 6);
  const int j = tid & 63;
  float mu = (float)hp[bt * 768 + j];
  float lv = (float)hp[bt * 768 + 64 + j];
  float ev = eps[bt * 64 + j];
  ztil[bt * 64 + j] = mu + __expf(0.5f * lv) * ev;
  float term = 1.f + lv - mu * mu - __expf(lv);
#pragma unroll
  for (int s = 1; s < 64; s <<= 1) term += __shfl_xor(term, s);
  __shared__ float red[4];
  if ((tid & 63) == 0) red[tid >> 6] = term;
  __syncthreads();
  if (tid == 0) klp[blk] = red[0] + red[1] + red[2] + red[3];
}

__global__ __launch_bounds__(256) void klred(const float* __restrict__ klp,
                                             float* __restrict__ out) {
  const int tid = threadIdx.x;
  float s = 0.f;
  for (int i = tid; i < 16384; i += 256) s += klp[i];
#pragma unroll
  for (int st = 1; st < 64; st <<= 1) s += __shfl_xor(s, st);
  __shared__ float red[4];
  if ((tid & 63) == 0) red[tid >> 6] = s;
  __syncthreads();
  if (tid == 0) out[0] = (red[0] + red[1] + red[2] + red[3]) * (-0.5f / 65536.f);
}

// ---------------- sequential z-scan: ONE wave per batch element ----------------
__global__ __launch_bounds__(64, 4) void z_scan(
    const half_t* __restrict__ hp,  // pre at col offset 128, stride 768
    const float* __restrict__ zt_arr,
    const uint32* __restrict__ w1z,  // [64][64] thread-k layout
    const float* __restrict__ sw_w2, const float* __restrict__ sw_b2,
    float* __restrict__ z_out, float* __restrict__ beta_out) {
  const int b = blockIdx.x;
  const int k = threadIdx.x;  // 0..63; owns hid rows k and k+64
  uv16 z0a, z0b, z1a, z1b;    // 64 weights in named vectors
  {
#define LDZ(vec, base)                                    \
  _Pragma("unroll") for (int e = 0; e < 16; ++e) vec[e] = \
      w1z[((base) + e) * 64 + k];
    LDZ(z0a, 0); LDZ(z0b, 16); LDZ(z1a, 32); LDZ(z1b, 48);
#undef LDZ
  }
  const float w2k0 = sw_w2[k], w2k1 = sw_w2[k + 64], b2 = sw_b2[0];
  __shared__ uint32 zbuf[2][32];
  if (k < 32) { zbuf[0][k] = 0; zbuf[1][k] = 0; }
  __syncthreads();
  float zf = 0.f;
  const size_t bt0 = (size_t)b * T_;
  float pre0n = (float)hp[bt0 * 768 + 128 + k];
  float pre1n = (float)hp[bt0 * 768 + 192 + k];
  float ztn = zt_arr[bt0 * 64 + k];
  for (int t = 0; t < T_; ++t) {
    const int cur = t & 1;
    const float pre0 = pre0n, pre1 = pre1n, zt = ztn;
    const int tn = (t < T_ - 1) ? t + 1 : t;
    pre0n = (float)hp[(bt0 + tn) * 768 + 128 + k];
    pre1n = (float)hp[(bt0 + tn) * 768 + 192 + k];
    ztn = zt_arr[(bt0 + tn) * 64 + k];
    float a0 = 0, a1 = 0, a2 = 0, a3 = 0;
#pragma unroll
    for (int q = 0; q < 8; ++q) {
      uint4 u = *(const uint4*)&zbuf[cur][q * 4];
      const int m = q * 4;
      a0 = fdot2f(WSEL(z0a, z0b, m),     bch2(u.x), a0);
      a1 = fdot2f(WSEL(z0a, z0b, m + 1), bch2(u.y), a1);
      a0 = fdot2f(WSEL(z0a, z0b, m + 2), bch2(u.z), a0);
      a1 = fdot2f(WSEL(z0a, z0b, m + 3), bch2(u.w), a1);
      a2 = fdot2f(WSEL(z1a, z1b, m),     bch2(u.x), a2);
      a3 = fdot2f(WSEL(z1a, z1b, m + 1), bch2(u.y), a3);
      a2 = fdot2f(WSEL(z1a, z1b, m + 2), bch2(u.z), a2);
      a3 = fdot2f(WSEL(z1a, z1b, m + 3), bch2(u.w), a3);
    }
    float hid0 = fmaxf(pre0 + a0 + a1, 0.f);
    float hid1 = fmaxf(pre1 + a2 + a3, 0.f);
    float v = fmaf(hid0, w2k0, hid1 * w2k1);
#pragma unroll
    for (int s = 1; s < 64; s <<= 1) v += __shfl_xor(v, s);
    const float beta = sigmf(v + b2);
    zf = beta * zt + (1.f - beta) * zf;
    z_out[(bt0 + t) * 64 + k] = zf;
    if (k == 0) beta_out[bt0 + t] = beta;
    float zo = __shfl_xor(zf, 1);
    if ((k & 1) == 0) zbuf[cur ^ 1][k >> 1] = pack2(zf, zo);
    asm volatile("s_waitcnt lgkmcnt(0)" ::: "memory");  // single-wave LDS ordering
  }
}

extern "C" void kernel_launch(void* const* d_in, const int* in_sizes, int n_in,
                              void* d_out, int out_size, void* d_ws, size_t ws_size,
                              hipStream_t stream) {
  (void)in_sizes; (void)n_in; (void)out_size;
  const float* e_seq  = (const float*)d_in[0];
  const float* eps    = (const float*)d_in[1];
  const float* w_ih_f = (const float*)d_in[2];
  const float* w_hh_f = (const float*)d_in[3];
  const float* b_ih_f = (const float*)d_in[4];
  const float* b_hh_f = (const float*)d_in[5];
  const float* w_ih_b = (const float*)d_in[6];
  const float* w_hh_b = (const float*)d_in[7];
  const float* b_ih_b = (const float*)d_in[8];
  const float* b_hh_b = (const float*)d_in[9];
  const float* mu_w   = (const float*)d_in[10];
  const float* mu_b   = (const float*)d_in[11];
  const float* lv_w   = (const float*)d_in[12];
  const float* lv_b   = (const float*)d_in[13];
  const float* sw_w1  = (const float*)d_in[14];
  const float* sw_b1  = (const float*)d_in[15];
  const float* sw_w2  = (const float*)d_in[16];
  const float* sw_b2  = (const float*)d_in[17];

  // workspace: [0,100663296) xpf; [100663296,201326592) xpb; tail: packed weights
  const size_t NEED = 201326592 + 1924096;
  if (ws_size < NEED) return;
  char* ws = (char*)d_ws;
  half_t* xpf = (half_t*)ws;
  half_t* xpb = (half_t*)(ws + 100663296);
  half_t* hp  = xpf + 512;                      // heads cols [512,768), stride 768
  float*  ztil = (float*)(ws + 100663296);      // alias xpb (dead after head passes)
  float*  klp  = (float*)(ws + 100663296 + 16777216);
  char* wr = ws + 201326592;
  uint32* wihf  = (uint32*)(wr);                //  393216 B
  uint32* wihb  = (uint32*)(wr + 393216);       //  393216 B
  uint32* wchf  = (uint32*)(wr + 786432);       //  131072 B
  uint32* wchb  = (uint32*)(wr + 917504);       //  131072 B
  uint32* wce2  = (uint32*)(wr + 1048576);      //   65536 B
  uint32* whh2  = (uint32*)(wr + 1114112);      //  786432 B
  uint32* w1z2  = (uint32*)(wr + 1900544);      //   16384 B
  float*  biasc = (float*)(wr + 1916928);       //    1024 B
  float*  biasf = (float*)(wr + 1917952);       //    3072 B
  float*  biasb = (float*)(wr + 1921024);       //    3072 B

  pack_w<<<1879, 256, 0, stream>>>(w_ih_f, w_ih_b, mu_w, lv_w, sw_w1, w_hh_f, w_hh_b,
                                   b_ih_f, b_ih_b, b_hh_f, b_hh_b, mu_b, lv_b, sw_b1,
                                   wihf, wihb, wchf, wchb, wce2, whh2, w1z2,
                                   biasc, biasf, biasb);
  gemm_t<1, 0><<<dim3(6, 512), 256, 0, stream>>>(e_seq, 256, (const half_t*)wihf, biasf, xpf, 768, 256);
  gemm_t<1, 0><<<dim3(6, 512), 256, 0, stream>>>(e_seq, 256, (const half_t*)wihb, biasb, xpb, 768, 256);
  gru_rec<<<128, 512, 0, stream>>>((uint32*)ws, whh2, b_hh_f, b_hh_b);
  gemm_t<0, 0><<<dim3(2, 512), 256, 0, stream>>>(xpf, 768, (const half_t*)wchf, biasc, hp, 768, 256);
  gemm_t<0, 1><<<dim3(2, 512), 256, 0, stream>>>(xpb, 768, (const half_t*)wchb, nullptr, hp, 768, 256);
  gemm_t<1, 1><<<dim3(1, 512), 256, 0, stream>>>(e_seq, 256, (const half_t*)wce2, nullptr, hp + 128, 768, 256);
  zkl<<<16384, 256, 0, stream>>>(hp, eps, ztil, klp);
  klred<<<1, 256, 0, stream>>>(klp, (float*)d_out + 4194304);
  z_scan<<<64, 64, 0, stream>>>(hp, ztil, w1z2, sw_w2, sw_b2, (float*)d_out, (float*)d_out + 4194305);
}

// Round 10
// 2706.859 us; speedup vs baseline: 1.2048x; 1.0036x over previous
//
#include <hip/hip_runtime.h>
#include <cstdint>

typedef _Float16 half_t;
typedef _Float16 half2_t __attribute__((ext_vector_type(2)));
typedef _Float16 h8_t __attribute__((ext_vector_type(8)));
typedef float f4_t __attribute__((ext_vector_type(4)));
typedef unsigned int uint32;
typedef uint32 uv16 __attribute__((ext_vector_type(16)));

static constexpr int B_ = 64, T_ = 1024;

#define DEV __device__ __forceinline__

DEV float fdot2f(half2_t a, half2_t b, float c) {
#if __has_builtin(__builtin_amdgcn_fdot2)
  return __builtin_amdgcn_fdot2(a, b, c, false);
#else
  return fmaf((float)a.x, (float)b.x, fmaf((float)a.y, (float)b.y, c));
#endif
}

DEV float fast_rcp(float x) { return __builtin_amdgcn_rcpf(x); }
DEV float sigmf(float x) { return fast_rcp(1.f + __expf(-x)); }
DEV float tanhf_(float x) { return 1.f - 2.f * fast_rcp(1.f + __expf(2.f * x)); }
DEV uint32 pack2(float a, float b) {
  half2_t h; h.x = (half_t)a; h.y = (half_t)b;
  return __builtin_bit_cast(uint32, h);
}
DEV half2_t bch2(uint32 u) { return __builtin_bit_cast(half2_t, u); }

DEV void gload_lds16(const void* g, void* l) {
  __builtin_amdgcn_global_load_lds(
      (const __attribute__((address_space(1))) uint32*)g,
      (__attribute__((address_space(3))) uint32*)l, 16, 0, 0);
}

// select element j (compile-time) from the (va,vb) 32-dword pair
#define WSEL(va, vb, j) bch2(((j) < 16) ? (va)[(j) & 15] : (vb)[((j) - 16) & 15])

// ---------------- weight packing (f32 -> packed f16) ----------------
__global__ __launch_bounds__(256) void pack_w(
    const float* __restrict__ w_ih_f, const float* __restrict__ w_ih_b,
    const float* __restrict__ mu_w, const float* __restrict__ lv_w,
    const float* __restrict__ sw_w1,
    const float* __restrict__ w_hh_f, const float* __restrict__ w_hh_b,
    const float* __restrict__ b_ih_f, const float* __restrict__ b_ih_b,
    const float* __restrict__ b_hh_f, const float* __restrict__ b_hh_b,
    const float* __restrict__ mu_b, const float* __restrict__ lv_b,
    const float* __restrict__ sw_b1,
    uint32* __restrict__ wihf, uint32* __restrict__ wihb,
    uint32* __restrict__ wchf, uint32* __restrict__ wchb, uint32* __restrict__ wce2,
    uint32* __restrict__ whh, uint32* __restrict__ w1z,
    float* __restrict__ biasc, float* __restrict__ biasf, float* __restrict__ biasb) {
  int id = blockIdx.x * 256 + threadIdx.x;
  if (id < 98304) { wihf[id] = pack2(w_ih_f[2*id], w_ih_f[2*id+1]); return; }
  id -= 98304;
  if (id < 98304) { wihb[id] = pack2(w_ih_b[2*id], w_ih_b[2*id+1]); return; }
  id -= 98304;
  if (id < 32768) {  // wchf (256x256): h_f columns of [mu_w|lv_w|w1_h]
    int n = id >> 7, c0 = (id & 127) * 2;
    const float* p = (n < 64)  ? mu_w + n * 512 + c0
                   : (n < 128) ? lv_w + (n - 64) * 512 + c0
                               : sw_w1 + (n - 128) * 832 + 256 + c0;
    wchf[id] = pack2(p[0], p[1]); return;
  }
  id -= 32768;
  if (id < 32768) {  // wchb (256x256): h_b columns
    int n = id >> 7, c0 = (id & 127) * 2;
    const float* p = (n < 64)  ? mu_w + n * 512 + 256 + c0
                   : (n < 128) ? lv_w + (n - 64) * 512 + 256 + c0
                               : sw_w1 + (n - 128) * 832 + 512 + c0;
    wchb[id] = pack2(p[0], p[1]); return;
  }
  id -= 32768;
  if (id < 16384) {  // wce2 (128x256): w1_e rows only
    int n = id >> 7, c0 = (id & 127) * 2;
    wce2[id] = pack2(sw_w1[n * 832 + c0], sw_w1[n * 832 + c0 + 1]); return;
  }
  id -= 16384;
  if (id < 196608) {  // whh2: [d][192][512] per-thread layout
    int dd = id / 98304, q = id % 98304;
    int j = q >> 9, t2 = q & 511;
    int rr = t2 >> 2, pp = t2 & 3;
    int gi = j >> 5, ck = j & 31;
    int g = gi >> 1, i = gi & 1;
    int row = 256 * g + 2 * rr + i;
    int k0 = pp * 64 + 2 * ck;
    const float* w = dd ? w_hh_b : w_hh_f;
    whh[id] = pack2(w[row * 256 + k0], w[row * 256 + k0 + 1]);
    return;
  }
  id -= 196608;
  if (id < 4096) {  // w1z2: [64][64] thread-k layout, rows (k, k+64)
    int j = id >> 6, kk = id & 63;
    int row = (j < 32) ? kk : kk + 64;
    int jj = j & 31;
    w1z[id] = pack2(sw_w1[row * 832 + 768 + 2 * jj], sw_w1[row * 832 + 768 + 2 * jj + 1]);
    return;
  }
  id -= 4096;
  if (id < 256) {
    biasc[id] = (id < 64) ? mu_b[id] : (id < 128) ? lv_b[id - 64] : sw_b1[id - 128];
    return;
  }
  id -= 256;
  if (id < 768) { biasf[id] = b_ih_f[id] + (id < 512 ? b_hh_f[id] : 0.f); return; }
  id -= 768;
  if (id < 768) { biasb[id] = b_ih_b[id] + (id < 512 ? b_hh_b[id] : 0.f); return; }
}

// ---------------- GEMM: C(MxN) = A(MxK) * B(N,K)^T [+bias] [+=C] ----------------
template <int AF32, int ACC>
__global__ __launch_bounds__(256) void gemm_t(
    const void* __restrict__ Ap, int lda,
    const half_t* __restrict__ Bw,  // (N,K) f16 row-major
    const float* __restrict__ bias,
    half_t* __restrict__ C, int ldc, int K) {
  __shared__ __align__(16) half_t smem[16384];
  half_t* As = smem;         // [128][64]
  half_t* Bs = smem + 8192;  // [128][64]
  const int tid = threadIdx.x;
  const int lane = tid & 63, w = tid >> 6;
  const int n0 = blockIdx.x * 128, m0 = blockIdx.y * 128;
  const int r8 = lane >> 3, c8 = lane & 7;
  f4_t acc[4][4];
  f4_t zero = {0.f, 0.f, 0.f, 0.f};
#pragma unroll
  for (int i = 0; i < 4; ++i)
#pragma unroll
    for (int j = 0; j < 4; ++j) acc[i][j] = zero;
  const int wm = (w >> 1) * 64, wn = (w & 1) * 64;
  for (int ks = 0; ks < K; ks += 64) {
    if constexpr (AF32) {
      const float* Af = (const float*)Ap;
#pragma unroll
      for (int it = 0; it < 4; ++it) {
        int c = it * 256 + tid;
        int row = c >> 3, coff = (c & 7) * 8;
        const float* ap = Af + (size_t)(m0 + row) * lda + ks + coff;
        float4 v0 = *(const float4*)ap;
        float4 v1 = *(const float4*)(ap + 4);
        uint4 u;
        u.x = pack2(v0.x, v0.y); u.y = pack2(v0.z, v0.w);
        u.z = pack2(v1.x, v1.y); u.w = pack2(v1.z, v1.w);
        *(uint4*)&As[(size_t)c * 8] = u;
      }
    } else {
      const half_t* Af = (const half_t*)Ap;
#pragma unroll
      for (int c = 0; c < 4; ++c) {
        int row = w * 32 + c * 8 + r8;
        gload_lds16(Af + (size_t)(m0 + row) * lda + ks + c8 * 8, As + (w * 4 + c) * 512);
      }
    }
#pragma unroll
    for (int c = 0; c < 4; ++c) {
      int row = w * 32 + c * 8 + r8;
      gload_lds16(Bw + (size_t)(n0 + row) * K + ks + c8 * 8, Bs + (w * 4 + c) * 512);
    }
    __syncthreads();
#pragma unroll
    for (int kk = 0; kk < 2; ++kk) {
      h8_t af[4], bf[4];
      const int ko = kk * 32 + (lane >> 4) * 8;
#pragma unroll
      for (int i = 0; i < 4; ++i) af[i] = *(const h8_t*)&As[(wm + i * 16 + (lane & 15)) * 64 + ko];
#pragma unroll
      for (int j = 0; j < 4; ++j) bf[j] = *(const h8_t*)&Bs[(wn + j * 16 + (lane & 15)) * 64 + ko];
#pragma unroll
      for (int i = 0; i < 4; ++i)
#pragma unroll
        for (int j = 0; j < 4; ++j)
          acc[i][j] = __builtin_amdgcn_mfma_f32_16x16x32_f16(af[i], bf[j], acc[i][j], 0, 0, 0);
    }
    __syncthreads();
  }
  const int cl4 = lane & 15, rl4 = lane >> 4;
#pragma unroll
  for (int j = 0; j < 4; ++j) {
    float bj = bias ? bias[n0 + wn + j * 16 + cl4] : 0.f;
#pragma unroll
    for (int i = 0; i < 4; ++i)
#pragma unroll
      for (int q = 0; q < 4; ++q) {
        int rl = wm + i * 16 + rl4 * 4 + q;
        int cc = wn + j * 16 + cl4;
        smem[rl * 128 + cc] = (half_t)(acc[i][j][q] + bj);
      }
  }
  __syncthreads();
#pragma unroll
  for (int it = 0; it < 8; ++it) {
    int idx = it * 256 + tid;
    int row = idx >> 4, colc = idx & 15;
    uint4 v = *(const uint4*)&smem[row * 128 + colc * 8];
    half_t* cp = C + (size_t)(m0 + row) * ldc + n0 + colc * 8;
    if constexpr (ACC) {
      uint4 o = *(const uint4*)cp;
      h8_t vv = __builtin_bit_cast(h8_t, v) + __builtin_bit_cast(h8_t, o);
      v = __builtin_bit_cast(uint4, vv);
    }
    *(uint4*)cp = v;
  }
}

// ======== hybrid VGPR/AGPR weight residency, pipelined reads ========
// AGPR names for j = 64..191 (128 regs)
#define WA_ALL(X) \
  X(64) X(65) X(66) X(67) X(68) X(69) X(70) X(71) X(72) X(73) X(74) X(75) X(76) X(77) X(78) X(79) \
  X(80) X(81) X(82) X(83) X(84) X(85) X(86) X(87) X(88) X(89) X(90) X(91) X(92) X(93) X(94) X(95) \
  X(96) X(97) X(98) X(99) X(100) X(101) X(102) X(103) X(104) X(105) X(106) X(107) X(108) X(109) X(110) X(111) \
  X(112) X(113) X(114) X(115) X(116) X(117) X(118) X(119) X(120) X(121) X(122) X(123) X(124) X(125) X(126) X(127) \
  X(128) X(129) X(130) X(131) X(132) X(133) X(134) X(135) X(136) X(137) X(138) X(139) X(140) X(141) X(142) X(143) \
  X(144) X(145) X(146) X(147) X(148) X(149) X(150) X(151) X(152) X(153) X(154) X(155) X(156) X(157) X(158) X(159) \
  X(160) X(161) X(162) X(163) X(164) X(165) X(166) X(167) X(168) X(169) X(170) X(171) X(172) X(173) X(174) X(175) \
  X(176) X(177) X(178) X(179) X(180) X(181) X(182) X(183) X(184) X(185) X(186) X(187) X(188) X(189) X(190) X(191)

#define WDECL(n) uint32 wa##n;
#define WLOAD(n) asm volatile("v_accvgpr_write_b32 %0, %1" : "=a"(wa##n) : "v"(wp[(n) * 512]));
// volatile AGPR->VGPR read (volatile: keeps reads in program order, no CSE)
#define ARD(T, W) asm volatile("v_accvgpr_read_b32 %0, %1" : "=v"(T) : "a"(W));
// VGPR weight select (compile-time j in 0..63 across wv0..wv3)
#define WV(j) bch2(((j) < 16) ? wv0[(j) & 15] : ((j) < 32) ? wv1[(j) & 15] \
                 : ((j) < 48) ? wv2[(j) & 15] : wv3[(j) & 15])
// COL_A: uses tA quad (read 1 col earlier), prefetches NEXT col's quad into tB.
// Read->use distance ~12-15 instructions (~24-30 cyc) >= accvgpr hazard (~24 cyc, R7/R9 fit).
#define COL_A(j, N0, N1, N2, N3, hh)        \
  {                                         \
    ARD(tB0, N0) ARD(tB1, N1) ARD(tB2, N2) ARD(tB3, N3) \
    a00 = fdot2f(WV(j), hh, a00);           \
    a01 = fdot2f(bch2(tA0), hh, a01);       \
    a10 = fdot2f(WV((j) + 32), hh, a10);    \
    a11 = fdot2f(bch2(tA1), hh, a11);       \
    a02 = fdot2f(bch2(tA2), hh, a02);       \
    a12 = fdot2f(bch2(tA3), hh, a12);       \
  }
#define COL_B(j, N0, N1, N2, N3, hh)        \
  {                                         \
    ARD(tA0, N0) ARD(tA1, N1) ARD(tA2, N2) ARD(tA3, N3) \
    a00 = fdot2f(WV(j), hh, a00);           \
    a01 = fdot2f(bch2(tB0), hh, a01);       \
    a10 = fdot2f(WV((j) + 32), hh, a10);    \
    a11 = fdot2f(bch2(tB1), hh, a11);       \
    a02 = fdot2f(bch2(tB2), hh, a02);       \
    a12 = fdot2f(bch2(tB3), hh, a12);       \
  }
#define COL_B_LAST(j, hh)                   \
  {                                         \
    a00 = fdot2f(WV(j), hh, a00);           \
    a01 = fdot2f(bch2(tB0), hh, a01);       \
    a10 = fdot2f(WV((j) + 32), hh, a10);    \
    a11 = fdot2f(bch2(tB1), hh, a11);       \
    a02 = fdot2f(bch2(tB2), hh, a02);       \
    a12 = fdot2f(bch2(tB3), hh, a12);       \
  }

// ---------------- GRU recurrence: 64 weights in VGPR + 128 in AGPR ----------------
// 128 WGs = (b, dir); 512 threads = 128 r-groups (2 hidden units) x 4 K-slices.
__global__ __launch_bounds__(512) void gru_rec(
    uint32* __restrict__ xp,          // [2][B][T][384] dwords (f16 pairs)
    const uint32* __restrict__ whh2,  // [2][192][512]
    const float* __restrict__ bhh_f, const float* __restrict__ bhh_b) {
  const int wg = blockIdx.x;
  const int d = wg >> 6, b = wg & 63;
  const int tid = threadIdx.x;
  const int r = tid >> 2, p = tid & 3;
  __shared__ uint32 hb[2][144];  // 4 slices x (32 data + 4 pad) dwords
  if (tid < 144) { hb[0][tid] = 0; hb[1][tid] = 0; }
  uv16 wv0, wv1, wv2, wv3;  // weights j=0..63 (gates a00, a10)
  WA_ALL(WDECL)
  {
    const uint32* wp = whh2 + (size_t)d * 98304 + tid;
#pragma unroll
    for (int e = 0; e < 16; ++e) {
      wv0[e] = wp[(size_t)(e) * 512];
      wv1[e] = wp[(size_t)(16 + e) * 512];
      wv2[e] = wp[(size_t)(32 + e) * 512];
      wv3[e] = wp[(size_t)(48 + e) * 512];
    }
    WA_ALL(WLOAD)
  }
  const float* bhh = d ? bhh_b : bhh_f;
  const float bhn0 = bhh[512 + 2 * r], bhn1 = bhh[512 + 2 * r + 1];
  uint32* xpu = xp + ((size_t)d * B_ + b) * T_ * 384;
  float h0 = 0.f, h1 = 0.f;
  const int dt = d ? -1 : 1;
  int t = d ? (T_ - 1) : 0;
  uint32 xr_n = 0, xz_n = 0, xn_n = 0;
  if (p == 0) {
    const uint32* rowp = xpu + (size_t)t * 384;
    xr_n = rowp[r]; xz_n = rowp[128 + r]; xn_n = rowp[256 + r];
  }
  const int rdbase = p * 36;
  const int wslice = (r >> 5) * 36 + (r & 31);
  __syncthreads();
  for (int step = 0; step < T_; ++step) {
    const int cur = step & 1;
    const uint32 xr = xr_n, xz = xz_n, xn = xn_n;
    const int tn = (step < T_ - 1) ? (t + dt) : t;
    if (p == 0) {
      const uint32* rowp = xpu + (size_t)tn * 384;
      xr_n = rowp[r]; xz_n = rowp[128 + r]; xn_n = rowp[256 + r];
    }
    float a00 = 0, a10 = 0, a01 = 0, a11 = 0, a02 = 0, a12 = 0;
    uint32 tA0, tA1, tA2, tA3, tB0, tB1, tB2, tB3;
    const uint32* hc = &hb[cur][rdbase];
    // prologue: col 0's AGPR quad
    ARD(tA0, wa64) ARD(tA1, wa96) ARD(tA2, wa128) ARD(tA3, wa160)
    {  // columns 0..7
      uint4 u0 = *(const uint4*)(hc + 0);
      uint4 u1 = *(const uint4*)(hc + 4);
      half2_t g0 = bch2(u0.x), g1 = bch2(u0.y), g2 = bch2(u0.z), g3 = bch2(u0.w);
      half2_t g4 = bch2(u1.x), g5 = bch2(u1.y), g6 = bch2(u1.z), g7 = bch2(u1.w);
      COL_A(0, wa65, wa97, wa129, wa161, g0)
      COL_B(1, wa66, wa98, wa130, wa162, g1)
      COL_A(2, wa67, wa99, wa131, wa163, g2)
      COL_B(3, wa68, wa100, wa132, wa164, g3)
      COL_A(4, wa69, wa101, wa133, wa165, g4)
      COL_B(5, wa70, wa102, wa134, wa166, g5)
      COL_A(6, wa71, wa103, wa135, wa167, g6)
      COL_B(7, wa72, wa104, wa136, wa168, g7)
    }
    {  // columns 8..15
      uint4 u0 = *(const uint4*)(hc + 8);
      uint4 u1 = *(const uint4*)(hc + 12);
      half2_t g0 = bch2(u0.x), g1 = bch2(u0.y), g2 = bch2(u0.z), g3 = bch2(u0.w);
      half2_t g4 = bch2(u1.x), g5 = bch2(u1.y), g6 = bch2(u1.z), g7 = bch2(u1.w);
      COL_A(8, wa73, wa105, wa137, wa169, g0)
      COL_B(9, wa74, wa106, wa138, wa170, g1)
      COL_A(10, wa75, wa107, wa139, wa171, g2)
      COL_B(11, wa76, wa108, wa140, wa172, g3)
      COL_A(12, wa77, wa109, wa141, wa173, g4)
      COL_B(13, wa78, wa110, wa142, wa174, g5)
      COL_A(14, wa79, wa111, wa143, wa175, g6)
      COL_B(15, wa80, wa112, wa144, wa176, g7)
    }
    {  // columns 16..23
      uint4 u0 = *(const uint4*)(hc + 16);
      uint4 u1 = *(const uint4*)(hc + 20);
      half2_t g0 = bch2(u0.x), g1 = bch2(u0.y), g2 = bch2(u0.z), g3 = bch2(u0.w);
      half2_t g4 = bch2(u1.x), g5 = bch2(u1.y), g6 = bch2(u1.z), g7 = bch2(u1.w);
      COL_A(16, wa81, wa113, wa145, wa177, g0)
      COL_B(17, wa82, wa114, wa146, wa178, g1)
      COL_A(18, wa83, wa115, wa147, wa179, g2)
      COL_B(19, wa84, wa116, wa148, wa180, g3)
      COL_A(20, wa85, wa117, wa149, wa181, g4)
      COL_B(21, wa86, wa118, wa150, wa182, g5)
      COL_A(22, wa87, wa119, wa151, wa183, g6)
      COL_B(23, wa88, wa120, wa152, wa184, g7)
    }
    {  // columns 24..31
      uint4 u0 = *(const uint4*)(hc + 24);
      uint4 u1 = *(const uint4*)(hc + 28);
      half2_t g0 = bch2(u0.x), g1 = bch2(u0.y), g2 = bch2(u0.z), g3 = bch2(u0.w);
      half2_t g4 = bch2(u1.x), g5 = bch2(u1.y), g6 = bch2(u1.z), g7 = bch2(u1.w);
      COL_A(24, wa89, wa121, wa153, wa185, g0)
      COL_B(25, wa90, wa122, wa154, wa186, g1)
      COL_A(26, wa91, wa123, wa155, wa187, g2)
      COL_B(27, wa92, wa124, wa156, wa188, g3)
      COL_A(28, wa93, wa125, wa157, wa189, g4)
      COL_B(29, wa94, wa126, wa158, wa190, g5)
      COL_A(30, wa95, wa127, wa159, wa191, g6)
      COL_B_LAST(31, g7)
    }
    a00 += __shfl_xor(a00, 1); a00 += __shfl_xor(a00, 2);
    a10 += __shfl_xor(a10, 1); a10 += __shfl_xor(a10, 2);
    a01 += __shfl_xor(a01, 1); a01 += __shfl_xor(a01, 2);
    a11 += __shfl_xor(a11, 1); a11 += __shfl_xor(a11, 2);
    a02 += __shfl_xor(a02, 1); a02 += __shfl_xor(a02, 2);
    a12 += __shfl_xor(a12, 1); a12 += __shfl_xor(a12, 2);
    if (p == 0) {
      half2_t xrv = bch2(xr), xzv = bch2(xz), xnv = bch2(xn);
      float r0 = sigmf((float)xrv.x + a00);
      float z0 = sigmf((float)xzv.x + a01);
      float n0 = tanhf_((float)xnv.x + r0 * (a02 + bhn0));
      h0 = (1.f - z0) * n0 + z0 * h0;
      float r1 = sigmf((float)xrv.y + a10);
      float z1 = sigmf((float)xzv.y + a11);
      float n1 = tanhf_((float)xnv.y + r1 * (a12 + bhn1));
      h1 = (1.f - z1) * n1 + z1 * h1;
      uint32 ph = pack2(h0, h1);
      hb[cur ^ 1][wslice] = ph;
      xpu[(size_t)t * 384 + r] = ph;  // in-place h store (xr slot dead)
    }
    __syncthreads();
    t = tn;
  }
}

// ---------------- z_tilde + KL partials ----------------
__global__ __launch_bounds__(256) void zkl(const half_t* __restrict__ hp,  // stride 768
                                           const float* __restrict__ eps,
                                           float* __restrict__ ztil,
                                           float* __restrict__ klp) {
  const int blk = blockIdx.x, tid = threadIdx.x;
  const size_t bt = (size_t)blk * 4 + (tid >> 6);
  const int j = tid & 63;
  float mu = (float)hp[bt * 768 + j];
  float lv = (float)hp[bt * 768 + 64 + j];
  float ev = eps[bt * 64 + j];
  ztil[bt * 64 + j] = mu + __expf(0.5f * lv) * ev;
  float term = 1.f + lv - mu * mu - __expf(lv);
#pragma unroll
  for (int s = 1; s < 64; s <<= 1) term += __shfl_xor(term, s);
  __shared__ float red[4];
  if ((tid & 63) == 0) red[tid >> 6] = term;
  __syncthreads();
  if (tid == 0) klp[blk] = red[0] + red[1] + red[2] + red[3];
}

__global__ __launch_bounds__(256) void klred(const float* __restrict__ klp,
                                             float* __restrict__ out) {
  const int tid = threadIdx.x;
  float s = 0.f;
  for (int i = tid; i < 16384; i += 256) s += klp[i];
#pragma unroll
  for (int st = 1; st < 64; st <<= 1) s += __shfl_xor(s, st);
  __shared__ float red[4];
  if ((tid & 63) == 0) red[tid >> 6] = s;
  __syncthreads();
  if (tid == 0) out[0] = (red[0] + red[1] + red[2] + red[3]) * (-0.5f / 65536.f);
}

// ---------------- sequential z-scan: ONE wave per batch element ----------------
__global__ __launch_bounds__(64, 4) void z_scan(
    const half_t* __restrict__ hp,  // pre at col offset 128, stride 768
    const float* __restrict__ zt_arr,
    const uint32* __restrict__ w1z,  // [64][64] thread-k layout
    const float* __restrict__ sw_w2, const float* __restrict__ sw_b2,
    float* __restrict__ z_out, float* __restrict__ beta_out) {
  const int b = blockIdx.x;
  const int k = threadIdx.x;  // 0..63; owns hid rows k and k+64
  uv16 z0a, z0b, z1a, z1b;    // 64 weights in named vectors
  {
#define LDZ(vec, base)                                    \
  _Pragma("unroll") for (int e = 0; e < 16; ++e) vec[e] = \
      w1z[((base) + e) * 64 + k];
    LDZ(z0a, 0); LDZ(z0b, 16); LDZ(z1a, 32); LDZ(z1b, 48);
#undef LDZ
  }
  const float w2k0 = sw_w2[k], w2k1 = sw_w2[k + 64], b2 = sw_b2[0];
  __shared__ uint32 zbuf[2][32];
  if (k < 32) { zbuf[0][k] = 0; zbuf[1][k] = 0; }
  __syncthreads();
  float zf = 0.f;
  const size_t bt0 = (size_t)b * T_;
  float pre0n = (float)hp[bt0 * 768 + 128 + k];
  float pre1n = (float)hp[bt0 * 768 + 192 + k];
  float ztn = zt_arr[bt0 * 64 + k];
  for (int t = 0; t < T_; ++t) {
    const int cur = t & 1;
    const float pre0 = pre0n, pre1 = pre1n, zt = ztn;
    const int tn = (t < T_ - 1) ? t + 1 : t;
    pre0n = (float)hp[(bt0 + tn) * 768 + 128 + k];
    pre1n = (float)hp[(bt0 + tn) * 768 + 192 + k];
    ztn = zt_arr[(bt0 + tn) * 64 + k];
    float a0 = 0, a1 = 0, a2 = 0, a3 = 0;
#pragma unroll
    for (int q = 0; q < 8; ++q) {
      uint4 u = *(const uint4*)&zbuf[cur][q * 4];
      const int m = q * 4;
      a0 = fdot2f(WSEL(z0a, z0b, m),     bch2(u.x), a0);
      a1 = fdot2f(WSEL(z0a, z0b, m + 1), bch2(u.y), a1);
      a0 = fdot2f(WSEL(z0a, z0b, m + 2), bch2(u.z), a0);
      a1 = fdot2f(WSEL(z0a, z0b, m + 3), bch2(u.w), a1);
      a2 = fdot2f(WSEL(z1a, z1b, m),     bch2(u.x), a2);
      a3 = fdot2f(WSEL(z1a, z1b, m + 1), bch2(u.y), a3);
      a2 = fdot2f(WSEL(z1a, z1b, m + 2), bch2(u.z), a2);
      a3 = fdot2f(WSEL(z1a, z1b, m + 3), bch2(u.w), a3);
    }
    float hid0 = fmaxf(pre0 + a0 + a1, 0.f);
    float hid1 = fmaxf(pre1 + a2 + a3, 0.f);
    float v = fmaf(hid0, w2k0, hid1 * w2k1);
#pragma unroll
    for (int s = 1; s < 64; s <<= 1) v += __shfl_xor(v, s);
    const float beta = sigmf(v + b2);
    zf = beta * zt + (1.f - beta) * zf;
    z_out[(bt0 + t) * 64 + k] = zf;
    if (k == 0) beta_out[bt0 + t] = beta;
    float zo = __shfl_xor(zf, 1);
    if ((k & 1) == 0) zbuf[cur ^ 1][k >> 1] = pack2(zf, zo);
    asm volatile("s_waitcnt lgkmcnt(0)" ::: "memory");  // single-wave LDS ordering
  }
}

extern "C" void kernel_launch(void* const* d_in, const int* in_sizes, int n_in,
                              void* d_out, int out_size, void* d_ws, size_t ws_size,
                              hipStream_t stream) {
  (void)in_sizes; (void)n_in; (void)out_size;
  const float* e_seq  = (const float*)d_in[0];
  const float* eps    = (const float*)d_in[1];
  const float* w_ih_f = (const float*)d_in[2];
  const float* w_hh_f = (const float*)d_in[3];
  const float* b_ih_f = (const float*)d_in[4];
  const float* b_hh_f = (const float*)d_in[5];
  const float* w_ih_b = (const float*)d_in[6];
  const float* w_hh_b = (const float*)d_in[7];
  const float* b_ih_b = (const float*)d_in[8];
  const float* b_hh_b = (const float*)d_in[9];
  const float* mu_w   = (const float*)d_in[10];
  const float* mu_b   = (const float*)d_in[11];
  const float* lv_w   = (const float*)d_in[12];
  const float* lv_b   = (const float*)d_in[13];
  const float* sw_w1  = (const float*)d_in[14];
  const float* sw_b1  = (const float*)d_in[15];
  const float* sw_w2  = (const float*)d_in[16];
  const float* sw_b2  = (const float*)d_in[17];

  // workspace: [0,100663296) xpf; [100663296,201326592) xpb; tail: packed weights
  const size_t NEED = 201326592 + 1924096;
  if (ws_size < NEED) return;
  char* ws = (char*)d_ws;
  half_t* xpf = (half_t*)ws;
  half_t* xpb = (half_t*)(ws + 100663296);
  half_t* hp  = xpf + 512;                      // heads cols [512,768), stride 768
  float*  ztil = (float*)(ws + 100663296);      // alias xpb (dead after head passes)
  float*  klp  = (float*)(ws + 100663296 + 16777216);
  char* wr = ws + 201326592;
  uint32* wihf  = (uint32*)(wr);                //  393216 B
  uint32* wihb  = (uint32*)(wr + 393216);       //  393216 B
  uint32* wchf  = (uint32*)(wr + 786432);       //  131072 B
  uint32* wchb  = (uint32*)(wr + 917504);       //  131072 B
  uint32* wce2  = (uint32*)(wr + 1048576);      //   65536 B
  uint32* whh2  = (uint32*)(wr + 1114112);      //  786432 B
  uint32* w1z2  = (uint32*)(wr + 1900544);      //   16384 B
  float*  biasc = (float*)(wr + 1916928);       //    1024 B
  float*  biasf = (float*)(wr + 1917952);       //    3072 B
  float*  biasb = (float*)(wr + 1921024);       //    3072 B

  pack_w<<<1879, 256, 0, stream>>>(w_ih_f, w_ih_b, mu_w, lv_w, sw_w1, w_hh_f, w_hh_b,
                                   b_ih_f, b_ih_b, b_hh_f, b_hh_b, mu_b, lv_b, sw_b1,
                                   wihf, wihb, wchf, wchb, wce2, whh2, w1z2,
                                   biasc, biasf, biasb);
  gemm_t<1, 0><<<dim3(6, 512), 256, 0, stream>>>(e_seq, 256, (const half_t*)wihf, biasf, xpf, 768, 256);
  gemm_t<1, 0><<<dim3(6, 512), 256, 0, stream>>>(e_seq, 256, (const half_t*)wihb, biasb, xpb, 768, 256);
  gru_rec<<<128, 512, 0, stream>>>((uint32*)ws, whh2, b_hh_f, b_hh_b);
  gemm_t<0, 0><<<dim3(2, 512), 256, 0, stream>>>(xpf, 768, (const half_t*)wchf, biasc, hp, 768, 256);
  gemm_t<0, 1><<<dim3(2, 512), 256, 0, stream>>>(xpb, 768, (const half_t*)wchb, nullptr, hp, 768, 256);
  gemm_t<1, 1><<<dim3(1, 512), 256, 0, stream>>>(e_seq, 256, (const half_t*)wce2, nullptr, hp + 128, 768, 256);
  zkl<<<16384, 256, 0, stream>>>(hp, eps, ztil, klp);
  klred<<<1, 256, 0, stream>>>(klp, (float*)d_out + 4194304);
  z_scan<<<64, 64, 0, stream>>>(hp, ztil, w1z2, sw_w2, sw_b2, (float*)d_out, (float*)d_out + 4194305);
}